// Round 1
// baseline (288.250 us; speedup 1.0000x reference)
//
#include <hip/hip_runtime.h>
#include <math.h>

// Problem constants (from reference): B=8, N=2048, C_IN=3, D=64, K=8, LEVELS=3, H1=256, H2=128
#define BB   8
#define NN   2048
#define BN   16384   // B*N
#define DD   64
#define KNB  8
#define H1D  256
#define H2D  128

__device__ __forceinline__ float leaky(float v){ return v > 0.f ? v : 0.2f*v; }

// ---------------------------------------------------------------------------
// K1: per-point feature transform + suppressor weights.
// wave per point, lane = feature dim d (64).
// feat = leaky((x@W1 + b1)*g1 + be1);  fw = sigmoid(relu(x@Ws1+bs1)@Ws2 + bs2)
// ---------------------------------------------------------------------------
__global__ __launch_bounds__(256) void k_feat_fw(
    const float* __restrict__ x,
    const float* __restrict__ W1, const float* __restrict__ b1,
    const float* __restrict__ g1, const float* __restrict__ be1,
    const float* __restrict__ Ws1, const float* __restrict__ bs1,
    const float* __restrict__ Ws2, const float* __restrict__ bs2,
    float* __restrict__ feat, float* __restrict__ fw)
{
    int lane = threadIdx.x & 63;
    int p = blockIdx.x * 4 + (threadIdx.x >> 6);
    float x0 = x[p*3+0], x1 = x[p*3+1], x2 = x[p*3+2];
    int d = lane;

    float f = x0*W1[d] + x1*W1[64+d] + x2*W1[128+d] + b1[d];
    f = leaky(f * g1[d] + be1[d]);
    feat[p*64 + d] = f;

    float h = x0*Ws1[d] + x1*Ws1[64+d] + x2*Ws1[128+d] + bs1[d];
    h = fmaxf(h, 0.f);
    float s[3];
    #pragma unroll
    for (int l = 0; l < 3; ++l) {
        float v = h * Ws2[d*3 + l];
        #pragma unroll
        for (int off = 32; off; off >>= 1) v += __shfl_xor(v, off, 64);
        s[l] = v;
    }
    if (lane < 3) fw[p*3 + lane] = 1.f / (1.f + expf(-(s[lane] + bs2[lane])));
}

// ---------------------------------------------------------------------------
// K2: exact KNN (top-8 smallest d2, ties -> lower index, matching stable top_k).
// Block: 256 threads = 32 queries x 8 candidate-segments of 256 points.
// All of batch b's points cached in LDS as float4 (x,y,z,|x|^2): broadcast reads.
// Writes GLOBAL row index (b*N + m).
// ---------------------------------------------------------------------------
__global__ __launch_bounds__(256) void k_knn(const float* __restrict__ x, int* __restrict__ idxo)
{
    __shared__ float4 sp[NN];          // 32 KB
    __shared__ float  md[256*8];       // 8 KB
    __shared__ int    mi[256*8];       // 8 KB

    int b = blockIdx.x >> 6;
    int qbase = (blockIdx.x & 63) * 32;

    for (int i = threadIdx.x; i < NN; i += 256) {
        float a = x[(b*NN + i)*3 + 0];
        float c = x[(b*NN + i)*3 + 1];
        float e = x[(b*NN + i)*3 + 2];
        sp[i] = make_float4(a, c, e, a*a + c*c + e*e);
    }
    __syncthreads();

    int q   = qbase + (threadIdx.x & 31);
    int seg = threadIdx.x >> 5;
    float4 qv = sp[q];
    float q2 = qv.w;

    float bd[8]; int bi[8];
    #pragma unroll
    for (int j = 0; j < 8; ++j) { bd[j] = 1e30f; bi[j] = 1 << 30; }

    int m0 = seg * 256;
    for (int m = m0; m < m0 + 256; ++m) {
        float4 v = sp[m];
        float d2 = q2 + v.w - 2.f*(qv.x*v.x + qv.y*v.y + qv.z*v.z);
        if (d2 < bd[7]) {
            int pos = 7;
            #pragma unroll
            for (int j = 6; j >= 0; --j) if (d2 < bd[j]) pos = j;   // first j with d2 < bd[j]
            #pragma unroll
            for (int j = 7; j >= 1; --j) if (j > pos) { bd[j] = bd[j-1]; bi[j] = bi[j-1]; }
            #pragma unroll
            for (int j = 0; j < 8; ++j) if (j == pos) { bd[j] = d2; bi[j] = m; }
        }
    }

    __syncthreads();
    #pragma unroll
    for (int j = 0; j < 8; ++j) { md[threadIdx.x*8 + j] = bd[j]; mi[threadIdx.x*8 + j] = bi[j]; }
    __syncthreads();

    if (threadIdx.x < 32) {
        int qq = threadIdx.x;
        int ptr[8];
        #pragma unroll
        for (int sgi = 0; sgi < 8; ++sgi) ptr[sgi] = (sgi*32 + qq)*8;
        for (int out = 0; out < 8; ++out) {
            float bestd = 1e30f; int besti = 1 << 30; int bests = 0;
            #pragma unroll
            for (int sgi = 0; sgi < 8; ++sgi) {
                float dv = md[ptr[sgi]]; int iv = mi[ptr[sgi]];
                bool better = (dv < bestd) || (dv == bestd && iv < besti);
                if (better) { bestd = dv; besti = iv; bests = sgi; }
            }
            idxo[(b*NN + qbase + qq)*KNB + out] = b*NN + besti;
            #pragma unroll
            for (int sgi = 0; sgi < 8; ++sgi) if (sgi == bests) ptr[sgi]++;
        }
    }
}

// ---------------------------------------------------------------------------
// Generic fp32 tiled GEMM: C[M,*] (ldc) = epilogue(A[M,K] @ W[K,*] (ldw)).
// Tile 128x64, 256 threads, 4x8 micro-tile, BK=32.
// A_s row stride 36 -> the 8 row-groups hit distinct banks (b64 reads).
// Epilogue: optional +bias, *gam+bet, leaky.
// ---------------------------------------------------------------------------
__global__ __launch_bounds__(256) void k_gemm(
    const float* __restrict__ A, const float* __restrict__ W, float* __restrict__ C,
    int K, int ldw, int ldc,
    const float* __restrict__ bias, const float* __restrict__ gam,
    const float* __restrict__ bet, int act)
{
    __shared__ float A_s[128*36];   // 18 KB
    __shared__ float W_s[32*64];    // 8 KB

    int t  = threadIdx.x;
    int tx = t & 7;        // col group: 8 cols
    int ty = t >> 3;       // row group: 4 rows
    int rb = blockIdx.x * 128;
    int cb = blockIdx.y * 64;

    float acc[4][8];
    #pragma unroll
    for (int i = 0; i < 4; ++i)
        #pragma unroll
        for (int j = 0; j < 8; ++j) acc[i][j] = 0.f;

    for (int k0 = 0; k0 < K; k0 += 32) {
        #pragma unroll
        for (int it = 0; it < 4; ++it) {
            int i = t + it*256;            // 0..1023
            int r = i >> 3, kq = (i & 7) * 4;
            float4 v = *(const float4*)&A[(rb + r)*K + k0 + kq];
            *(float4*)&A_s[r*36 + kq] = v;
        }
        #pragma unroll
        for (int it = 0; it < 2; ++it) {
            int i = t + it*256;            // 0..511
            int k = i >> 4, cq = (i & 15) * 4;
            float4 v = *(const float4*)&W[(k0 + k)*ldw + cb + cq];
            *(float4*)&W_s[k*64 + cq] = v;
        }
        __syncthreads();

        #pragma unroll
        for (int kk = 0; kk < 32; kk += 2) {
            float2 a[4];
            #pragma unroll
            for (int i = 0; i < 4; ++i) a[i] = *(const float2*)&A_s[(ty*4 + i)*36 + kk];
            float4 w00 = *(const float4*)&W_s[ kk   *64 + tx*8];
            float4 w01 = *(const float4*)&W_s[ kk   *64 + tx*8 + 4];
            float4 w10 = *(const float4*)&W_s[(kk+1)*64 + tx*8];
            float4 w11 = *(const float4*)&W_s[(kk+1)*64 + tx*8 + 4];
            #pragma unroll
            for (int i = 0; i < 4; ++i) {
                float ax = a[i].x, ay = a[i].y;
                acc[i][0] = fmaf(ax, w00.x, acc[i][0]);
                acc[i][1] = fmaf(ax, w00.y, acc[i][1]);
                acc[i][2] = fmaf(ax, w00.z, acc[i][2]);
                acc[i][3] = fmaf(ax, w00.w, acc[i][3]);
                acc[i][4] = fmaf(ax, w01.x, acc[i][4]);
                acc[i][5] = fmaf(ax, w01.y, acc[i][5]);
                acc[i][6] = fmaf(ax, w01.z, acc[i][6]);
                acc[i][7] = fmaf(ax, w01.w, acc[i][7]);
                acc[i][0] = fmaf(ay, w10.x, acc[i][0]);
                acc[i][1] = fmaf(ay, w10.y, acc[i][1]);
                acc[i][2] = fmaf(ay, w10.z, acc[i][2]);
                acc[i][3] = fmaf(ay, w10.w, acc[i][3]);
                acc[i][4] = fmaf(ay, w11.x, acc[i][4]);
                acc[i][5] = fmaf(ay, w11.y, acc[i][5]);
                acc[i][6] = fmaf(ay, w11.z, acc[i][6]);
                acc[i][7] = fmaf(ay, w11.w, acc[i][7]);
            }
        }
        __syncthreads();
    }

    #pragma unroll
    for (int i = 0; i < 4; ++i) {
        int r = rb + ty*4 + i;
        int cbase = cb + tx*8;
        float vo[8];
        #pragma unroll
        for (int j = 0; j < 8; ++j) {
            int c = cbase + j;
            float v = acc[i][j];
            if (bias) v += bias[c];
            if (gam)  v = v * gam[c] + bet[c];
            if (act)  v = leaky(v);
            vo[j] = v;
        }
        *(float4*)&C[r*ldc + cbase]     = make_float4(vo[0], vo[1], vo[2], vo[3]);
        *(float4*)&C[r*ldc + cbase + 4] = make_float4(vo[4], vo[5], vo[6], vo[7]);
    }
}

// ---------------------------------------------------------------------------
// K4: gather-max edge conv + frequency weighting.
// agg[d] = max_j leaky((P[p][d] + b2[d] + Q[nb_j][d]) * g2[d] + be2[d])
// multi[l*64+d] = agg[d] * fw[l]
// wave per point, lane = d.
// ---------------------------------------------------------------------------
__global__ __launch_bounds__(256) void k_agg_multi(
    const float* __restrict__ PQ, const int* __restrict__ idx,
    const float* __restrict__ fw,
    const float* __restrict__ b2, const float* __restrict__ g2, const float* __restrict__ be2,
    float* __restrict__ multi)
{
    int lane = threadIdx.x & 63;
    int p = blockIdx.x * 4 + (threadIdx.x >> 6);
    float Pv = PQ[p*128 + lane] + b2[lane];
    float g = g2[lane], be = be2[lane];
    float mx = -1e30f;
    #pragma unroll
    for (int j = 0; j < KNB; ++j) {
        int nb = idx[p*KNB + j];
        float v = (Pv + PQ[nb*128 + 64 + lane]) * g + be;
        mx = fmaxf(mx, leaky(v));
    }
    float w0 = fw[p*3+0], w1 = fw[p*3+1], w2 = fw[p*3+2];
    multi[p*192 + lane]        = mx * w0;
    multi[p*192 + 64  + lane]  = mx * w1;
    multi[p*192 + 128 + lane]  = mx * w2;
}

// ---------------------------------------------------------------------------
// K7: delta = h2 @ Wf3 + bf3 (128 -> 3); out = x + 0.1*delta. wave per point.
// ---------------------------------------------------------------------------
__global__ __launch_bounds__(256) void k_out(
    const float* __restrict__ h2, const float* __restrict__ Wf3, const float* __restrict__ bf3,
    const float* __restrict__ x, float* __restrict__ out)
{
    int lane = threadIdx.x & 63;
    int p = blockIdx.x * 4 + (threadIdx.x >> 6);
    float v0 = h2[p*128 + lane], v1 = h2[p*128 + 64 + lane];
    #pragma unroll
    for (int l = 0; l < 3; ++l) {
        float s = v0 * Wf3[lane*3 + l] + v1 * Wf3[(64 + lane)*3 + l];
        #pragma unroll
        for (int off = 32; off; off >>= 1) s += __shfl_xor(s, off, 64);
        if (lane == l) out[p*3 + l] = x[p*3 + l] + 0.1f*(s + bf3[l]);
    }
}

// ---------------------------------------------------------------------------
extern "C" void kernel_launch(void* const* d_in, const int* in_sizes, int n_in,
                              void* d_out, int out_size, void* d_ws, size_t ws_size,
                              hipStream_t stream)
{
    const float* x    = (const float*)d_in[0];
    const float* W1   = (const float*)d_in[1];
    const float* b1   = (const float*)d_in[2];
    const float* g1   = (const float*)d_in[3];
    const float* be1  = (const float*)d_in[4];
    const float* W2   = (const float*)d_in[5];
    const float* b2   = (const float*)d_in[6];
    const float* g2   = (const float*)d_in[7];
    const float* be2  = (const float*)d_in[8];
    const float* Ws1  = (const float*)d_in[9];
    const float* bs1  = (const float*)d_in[10];
    const float* Ws2  = (const float*)d_in[11];
    const float* bs2  = (const float*)d_in[12];
    const float* Wf1  = (const float*)d_in[13];
    const float* bf1  = (const float*)d_in[14];
    const float* gf1  = (const float*)d_in[15];
    const float* bef1 = (const float*)d_in[16];
    const float* Wf2  = (const float*)d_in[17];
    const float* bf2  = (const float*)d_in[18];
    const float* gf2  = (const float*)d_in[19];
    const float* bef2 = (const float*)d_in[20];
    const float* Wf3  = (const float*)d_in[21];
    const float* bf3  = (const float*)d_in[22];
    float* out = (float*)d_out;

    char* ws = (char*)d_ws;
    // layout (MB offsets); later buffers reuse regions that are dead by then
    float* feat  = (float*)(ws + 0);                  // 4 MB   [BN,64]
    float* fw    = (float*)(ws + (4u  << 20));        // .75 MB [BN,3]
    int*   idx   = (int*)  (ws + (5u  << 20));        // .5 MB  [BN,8]
    float* PQ    = (float*)(ws + (6u  << 20));        // 8 MB   [BN,128]
    float* multi = (float*)(ws + (14u << 20));        // 12 MB  [BN,192]
    float* h1    = (float*)(ws + 0);                  // 16 MB  [BN,256] (feat/fw/idx/PQ dead)
    float* h2    = (float*)(ws + (16u << 20));        // 8 MB   [BN,128] (multi dead)

    k_feat_fw<<<BN/4, 256, 0, stream>>>(x, W1, b1, g1, be1, Ws1, bs1, Ws2, bs2, feat, fw);
    k_knn<<<BB*64, 256, 0, stream>>>(x, idx);
    // P = feat @ W2[:64]   -> PQ[:, 0:64]
    k_gemm<<<dim3(BN/128, 1), 256, 0, stream>>>(feat, W2,         PQ,      64, 64, 128,
                                                nullptr, nullptr, nullptr, 0);
    // Q = feat @ W2[64:]   -> PQ[:, 64:128]
    k_gemm<<<dim3(BN/128, 1), 256, 0, stream>>>(feat, W2 + 64*64, PQ + 64, 64, 64, 128,
                                                nullptr, nullptr, nullptr, 0);
    k_agg_multi<<<BN/4, 256, 0, stream>>>(PQ, idx, fw, b2, g2, be2, multi);
    // h1 = leaky((multi @ Wf1 + bf1)*gf1 + bef1)
    k_gemm<<<dim3(BN/128, H1D/64), 256, 0, stream>>>(multi, Wf1, h1, 192, H1D, H1D,
                                                     bf1, gf1, bef1, 1);
    // h2 = leaky((h1 @ Wf2 + bf2)*gf2 + bef2)
    k_gemm<<<dim3(BN/128, H2D/64), 256, 0, stream>>>(h1, Wf2, h2, H1D, H2D, H2D,
                                                     bf2, gf2, bef2, 1);
    k_out<<<BN/4, 256, 0, stream>>>(h2, Wf3, bf3, x, out);
}

// Round 2
// 251.823 us; speedup vs baseline: 1.1447x; 1.1447x over previous
//
#include <hip/hip_runtime.h>
#include <math.h>

// Problem constants (from reference): B=8, N=2048, C_IN=3, D=64, K=8, LEVELS=3, H1=256, H2=128
#define BB   8
#define NN   2048
#define BN   16384   // B*N
#define DD   64
#define KNB  8
#define H1D  256
#define H2D  128

__device__ __forceinline__ float leaky(float v){ return v > 0.f ? v : 0.2f*v; }

// ---------------------------------------------------------------------------
// K1: per-point feature transform + suppressor weights.
// wave per point, lane = feature dim d (64).
// ---------------------------------------------------------------------------
__global__ __launch_bounds__(256) void k_feat_fw(
    const float* __restrict__ x,
    const float* __restrict__ W1, const float* __restrict__ b1,
    const float* __restrict__ g1, const float* __restrict__ be1,
    const float* __restrict__ Ws1, const float* __restrict__ bs1,
    const float* __restrict__ Ws2, const float* __restrict__ bs2,
    float* __restrict__ feat, float* __restrict__ fw)
{
    int lane = threadIdx.x & 63;
    int p = blockIdx.x * 4 + (threadIdx.x >> 6);
    float x0 = x[p*3+0], x1 = x[p*3+1], x2 = x[p*3+2];
    int d = lane;

    float f = x0*W1[d] + x1*W1[64+d] + x2*W1[128+d] + b1[d];
    f = leaky(f * g1[d] + be1[d]);
    feat[p*64 + d] = f;

    float h = x0*Ws1[d] + x1*Ws1[64+d] + x2*Ws1[128+d] + bs1[d];
    h = fmaxf(h, 0.f);
    float s[3];
    #pragma unroll
    for (int l = 0; l < 3; ++l) {
        float v = h * Ws2[d*3 + l];
        #pragma unroll
        for (int off = 32; off; off >>= 1) v += __shfl_xor(v, off, 64);
        s[l] = v;
    }
    if (lane < 3) fw[p*3 + lane] = 1.f / (1.f + expf(-(s[lane] + bs2[lane])));
}

// ---------------------------------------------------------------------------
// K2: exact KNN (top-8 smallest d2, ties -> lower index, matching stable top_k).
// Block: 256 threads = 32 queries x 8 candidate-segments of 256 points.
// Branchless sorted bubble (cmp+cndmask), no divergent insert path.
// LDS: point cache (32 KB) overlaid by the merge arrays after the scan.
// ---------------------------------------------------------------------------
__global__ __launch_bounds__(256) void k_knn(const float* __restrict__ x, int* __restrict__ idxo)
{
    __shared__ __align__(16) char smem[32768];
    float4* sp = (float4*)smem;                 // 2048 * 16 B = 32 KB (scan phase)
    float*  md = (float*)smem;                  // 256*9 floats (merge phase, overlay)
    int*    mi = (int*)(smem + 256*9*4);        // 256*9 ints

    int b = blockIdx.x >> 6;
    int qbase = (blockIdx.x & 63) * 32;

    for (int i = threadIdx.x; i < NN; i += 256) {
        float a = x[(b*NN + i)*3 + 0];
        float c = x[(b*NN + i)*3 + 1];
        float e = x[(b*NN + i)*3 + 2];
        sp[i] = make_float4(a, c, e, a*a + c*c + e*e);
    }
    __syncthreads();

    int q   = qbase + (threadIdx.x & 31);
    int seg = threadIdx.x >> 5;
    float4 qv = sp[q];

    float bd[8]; int bi[8];
    #pragma unroll
    for (int j = 0; j < 8; ++j) { bd[j] = 1e30f; bi[j] = 1 << 30; }

    int m0 = seg * 256;
    #pragma unroll 4
    for (int m = m0; m < m0 + 256; ++m) {
        float4 v = sp[m];
        float d2 = qv.w + v.w - 2.f*(qv.x*v.x + qv.y*v.y + qv.z*v.z);
        // branchless insert of (d2, m) into sorted-ascending (bd, bi);
        // strict '<' keeps lower index first on exact ties (stream is index-ordered)
        float cd = d2; int ci = m;
        #pragma unroll
        for (int j = 0; j < 8; ++j) {
            bool c = cd < bd[j];
            float td = c ? bd[j] : cd;
            float nd = c ? cd   : bd[j];
            int   ti = c ? bi[j] : ci;
            int   ni = c ? ci   : bi[j];
            bd[j] = nd; bi[j] = ni; cd = td; ci = ti;
        }
    }

    __syncthreads();   // all sp reads done; safe to overlay
    #pragma unroll
    for (int j = 0; j < 8; ++j) { md[threadIdx.x*9 + j] = bd[j]; mi[threadIdx.x*9 + j] = bi[j]; }
    __syncthreads();

    if (threadIdx.x < 32) {
        int qq = threadIdx.x;
        int ptr[8];
        #pragma unroll
        for (int sgi = 0; sgi < 8; ++sgi) ptr[sgi] = (sgi*32 + qq)*9;
        for (int out = 0; out < 8; ++out) {
            float bestd = 1e30f; int besti = 1 << 30; int bests = 0;
            #pragma unroll
            for (int sgi = 0; sgi < 8; ++sgi) {
                float dv = md[ptr[sgi]]; int iv = mi[ptr[sgi]];
                bool better = (dv < bestd) || (dv == bestd && iv < besti);
                if (better) { bestd = dv; besti = iv; bests = sgi; }
            }
            idxo[(b*NN + qbase + qq)*KNB + out] = b*NN + besti;
            #pragma unroll
            for (int sgi = 0; sgi < 8; ++sgi) if (sgi == bests) ptr[sgi]++;
        }
    }
}

// ---------------------------------------------------------------------------
// Generic fp32 tiled GEMM: C[M,*] (ldc) = epilogue(A[M,K] @ W[K,*] (ldw)).
// Tile 128x64, 256 threads, 4x8 micro-tile, BK=32.
// ---------------------------------------------------------------------------
__global__ __launch_bounds__(256) void k_gemm(
    const float* __restrict__ A, const float* __restrict__ W, float* __restrict__ C,
    int K, int ldw, int ldc,
    const float* __restrict__ bias, const float* __restrict__ gam,
    const float* __restrict__ bet, int act)
{
    __shared__ float A_s[128*36];   // 18 KB
    __shared__ float W_s[32*64];    // 8 KB

    int t  = threadIdx.x;
    int tx = t & 7;        // col group: 8 cols
    int ty = t >> 3;       // row group: 4 rows
    int rb = blockIdx.x * 128;
    int cb = blockIdx.y * 64;

    float acc[4][8];
    #pragma unroll
    for (int i = 0; i < 4; ++i)
        #pragma unroll
        for (int j = 0; j < 8; ++j) acc[i][j] = 0.f;

    for (int k0 = 0; k0 < K; k0 += 32) {
        #pragma unroll
        for (int it = 0; it < 4; ++it) {
            int i = t + it*256;            // 0..1023
            int r = i >> 3, kq = (i & 7) * 4;
            float4 v = *(const float4*)&A[(rb + r)*K + k0 + kq];
            *(float4*)&A_s[r*36 + kq] = v;
        }
        #pragma unroll
        for (int it = 0; it < 2; ++it) {
            int i = t + it*256;            // 0..511
            int k = i >> 4, cq = (i & 15) * 4;
            float4 v = *(const float4*)&W[(k0 + k)*ldw + cb + cq];
            *(float4*)&W_s[k*64 + cq] = v;
        }
        __syncthreads();

        #pragma unroll
        for (int kk = 0; kk < 32; kk += 2) {
            float2 a[4];
            #pragma unroll
            for (int i = 0; i < 4; ++i) a[i] = *(const float2*)&A_s[(ty*4 + i)*36 + kk];
            float4 w00 = *(const float4*)&W_s[ kk   *64 + tx*8];
            float4 w01 = *(const float4*)&W_s[ kk   *64 + tx*8 + 4];
            float4 w10 = *(const float4*)&W_s[(kk+1)*64 + tx*8];
            float4 w11 = *(const float4*)&W_s[(kk+1)*64 + tx*8 + 4];
            #pragma unroll
            for (int i = 0; i < 4; ++i) {
                float ax = a[i].x, ay = a[i].y;
                acc[i][0] = fmaf(ax, w00.x, acc[i][0]);
                acc[i][1] = fmaf(ax, w00.y, acc[i][1]);
                acc[i][2] = fmaf(ax, w00.z, acc[i][2]);
                acc[i][3] = fmaf(ax, w00.w, acc[i][3]);
                acc[i][4] = fmaf(ax, w01.x, acc[i][4]);
                acc[i][5] = fmaf(ax, w01.y, acc[i][5]);
                acc[i][6] = fmaf(ax, w01.z, acc[i][6]);
                acc[i][7] = fmaf(ax, w01.w, acc[i][7]);
                acc[i][0] = fmaf(ay, w10.x, acc[i][0]);
                acc[i][1] = fmaf(ay, w10.y, acc[i][1]);
                acc[i][2] = fmaf(ay, w10.z, acc[i][2]);
                acc[i][3] = fmaf(ay, w10.w, acc[i][3]);
                acc[i][4] = fmaf(ay, w11.x, acc[i][4]);
                acc[i][5] = fmaf(ay, w11.y, acc[i][5]);
                acc[i][6] = fmaf(ay, w11.z, acc[i][6]);
                acc[i][7] = fmaf(ay, w11.w, acc[i][7]);
            }
        }
        __syncthreads();
    }

    #pragma unroll
    for (int i = 0; i < 4; ++i) {
        int r = rb + ty*4 + i;
        int cbase = cb + tx*8;
        float vo[8];
        #pragma unroll
        for (int j = 0; j < 8; ++j) {
            int c = cbase + j;
            float v = acc[i][j];
            if (bias) v += bias[c];
            if (gam)  v = v * gam[c] + bet[c];
            if (act)  v = leaky(v);
            vo[j] = v;
        }
        *(float4*)&C[r*ldc + cbase]     = make_float4(vo[0], vo[1], vo[2], vo[3]);
        *(float4*)&C[r*ldc + cbase + 4] = make_float4(vo[4], vo[5], vo[6], vo[7]);
    }
}

// ---------------------------------------------------------------------------
// K4: gather-max edge conv + frequency weighting.
// ---------------------------------------------------------------------------
__global__ __launch_bounds__(256) void k_agg_multi(
    const float* __restrict__ PQ, const int* __restrict__ idx,
    const float* __restrict__ fw,
    const float* __restrict__ b2, const float* __restrict__ g2, const float* __restrict__ be2,
    float* __restrict__ multi)
{
    int lane = threadIdx.x & 63;
    int p = blockIdx.x * 4 + (threadIdx.x >> 6);
    float Pv = PQ[p*128 + lane] + b2[lane];
    float g = g2[lane], be = be2[lane];
    float mx = -1e30f;
    #pragma unroll
    for (int j = 0; j < KNB; ++j) {
        int nb = idx[p*KNB + j];
        float v = (Pv + PQ[nb*128 + 64 + lane]) * g + be;
        mx = fmaxf(mx, leaky(v));
    }
    float w0 = fw[p*3+0], w1 = fw[p*3+1], w2 = fw[p*3+2];
    multi[p*192 + lane]        = mx * w0;
    multi[p*192 + 64  + lane]  = mx * w1;
    multi[p*192 + 128 + lane]  = mx * w2;
}

// ---------------------------------------------------------------------------
// K7: delta = h2 @ Wf3 + bf3 (128 -> 3); out = x + 0.1*delta. wave per point.
// ---------------------------------------------------------------------------
__global__ __launch_bounds__(256) void k_out(
    const float* __restrict__ h2, const float* __restrict__ Wf3, const float* __restrict__ bf3,
    const float* __restrict__ x, float* __restrict__ out)
{
    int lane = threadIdx.x & 63;
    int p = blockIdx.x * 4 + (threadIdx.x >> 6);
    float v0 = h2[p*128 + lane], v1 = h2[p*128 + 64 + lane];
    #pragma unroll
    for (int l = 0; l < 3; ++l) {
        float s = v0 * Wf3[lane*3 + l] + v1 * Wf3[(64 + lane)*3 + l];
        #pragma unroll
        for (int off = 32; off; off >>= 1) s += __shfl_xor(s, off, 64);
        if (lane == l) out[p*3 + l] = x[p*3 + l] + 0.1f*(s + bf3[l]);
    }
}

// ---------------------------------------------------------------------------
extern "C" void kernel_launch(void* const* d_in, const int* in_sizes, int n_in,
                              void* d_out, int out_size, void* d_ws, size_t ws_size,
                              hipStream_t stream)
{
    const float* x    = (const float*)d_in[0];
    const float* W1   = (const float*)d_in[1];
    const float* b1   = (const float*)d_in[2];
    const float* g1   = (const float*)d_in[3];
    const float* be1  = (const float*)d_in[4];
    const float* W2   = (const float*)d_in[5];
    const float* b2   = (const float*)d_in[6];
    const float* g2   = (const float*)d_in[7];
    const float* be2  = (const float*)d_in[8];
    const float* Ws1  = (const float*)d_in[9];
    const float* bs1  = (const float*)d_in[10];
    const float* Ws2  = (const float*)d_in[11];
    const float* bs2  = (const float*)d_in[12];
    const float* Wf1  = (const float*)d_in[13];
    const float* bf1  = (const float*)d_in[14];
    const float* gf1  = (const float*)d_in[15];
    const float* bef1 = (const float*)d_in[16];
    const float* Wf2  = (const float*)d_in[17];
    const float* bf2  = (const float*)d_in[18];
    const float* gf2  = (const float*)d_in[19];
    const float* bef2 = (const float*)d_in[20];
    const float* Wf3  = (const float*)d_in[21];
    const float* bf3  = (const float*)d_in[22];
    float* out = (float*)d_out;

    char* ws = (char*)d_ws;
    float* feat  = (float*)(ws + 0);                  // 4 MB   [BN,64]
    float* fw    = (float*)(ws + (4u  << 20));        // .75 MB [BN,3]
    int*   idx   = (int*)  (ws + (5u  << 20));        // .5 MB  [BN,8]
    float* PQ    = (float*)(ws + (6u  << 20));        // 8 MB   [BN,128]
    float* multi = (float*)(ws + (14u << 20));        // 12 MB  [BN,192]
    float* h1    = (float*)(ws + 0);                  // 16 MB  [BN,256] (feat/fw/idx/PQ dead)
    float* h2    = (float*)(ws + (16u << 20));        // 8 MB   [BN,128] (multi dead)

    k_feat_fw<<<BN/4, 256, 0, stream>>>(x, W1, b1, g1, be1, Ws1, bs1, Ws2, bs2, feat, fw);
    k_knn<<<BB*64, 256, 0, stream>>>(x, idx);
    k_gemm<<<dim3(BN/128, 1), 256, 0, stream>>>(feat, W2,         PQ,      64, 64, 128,
                                                nullptr, nullptr, nullptr, 0);
    k_gemm<<<dim3(BN/128, 1), 256, 0, stream>>>(feat, W2 + 64*64, PQ + 64, 64, 64, 128,
                                                nullptr, nullptr, nullptr, 0);
    k_agg_multi<<<BN/4, 256, 0, stream>>>(PQ, idx, fw, b2, g2, be2, multi);
    k_gemm<<<dim3(BN/128, H1D/64), 256, 0, stream>>>(multi, Wf1, h1, 192, H1D, H1D,
                                                     bf1, gf1, bef1, 1);
    k_gemm<<<dim3(BN/128, H2D/64), 256, 0, stream>>>(h1, Wf2, h2, H1D, H2D, H2D,
                                                     bf2, gf2, bef2, 1);
    k_out<<<BN/4, 256, 0, stream>>>(h2, Wf3, bf3, x, out);
}